// Round 17
// baseline (239.068 us; speedup 1.0000x reference)
//
#include <hip/hip_runtime.h>

// MultiRelationalSelfAttention: B=4,H=16,N=1024,D=64,T=4
//   S = Q@K^T * (1 + sum_t w[t,h]*A[t,b]) / 8 ; W = softmax(S); out = W@V
// Outputs (concat): out [B,H,N,D] f32, then attn_weight [B,H,N,N] f32.
//
// Round 17: r13 + TRANSPOSED QK^T MFMA (S^T = mfma(K,Q)).
//  A/B fragments share the same lane mapping, so swapping operand order
//  re-assigns acc[r] = S[q=l4][m = c*64+wv*16+hi4*4+r]: each thread owns 4
//  CONSECUTIVE m-columns of one q-row -> the bias gather becomes ONE float4
//  per edge type (4 loads/chunk vs 16 scalars), directly from the original
//  A layout — r11's isolated ~40us main-kernel win without pack_a's cost.
//  Softmax: 2 shfl_xor (16,32) + cross-wave LDS. P-pack: 16x8B stores.
//  K staging, phase 3, vectorized nt W-write = r13 verbatim.

#define NB 4
#define NH 16
#define NN 1024
#define ND 64
#define NT 4

typedef short s16x4 __attribute__((ext_vector_type(4)));
typedef short s16x8 __attribute__((ext_vector_type(8)));
typedef float f32x4 __attribute__((ext_vector_type(4)));

__device__ __forceinline__ short f2bf(float f) {
  return __builtin_bit_cast(short, (__bf16)f);
}
__device__ __forceinline__ float bf2f(short s) {
  return __builtin_bit_cast(float, ((unsigned)(unsigned short)s) << 16);
}

__device__ __forceinline__ void gload_lds16(const void* g, void* l) {
  __builtin_amdgcn_global_load_lds(
      (const __attribute__((address_space(1))) unsigned int*)g,
      (__attribute__((address_space(3))) unsigned int*)l, 16, 0, 0);
}

// ---------------- pre-kernel 1: K -> bf16 hi/lo, DMA-swizzled --------------
__global__ void pack_k(const float* __restrict__ Kg, short* __restrict__ Khi,
                       short* __restrict__ Klo) {
  int t = blockIdx.x * 256 + threadIdx.x;
  int p0 = t * 8;
  int bh = p0 >> 16;
  int rem = p0 & 65535;
  int chunk = rem >> 12;
  int e = rem & 4095;
  int r = e >> 6;
  int dd0 = e & 63;
  int d0 = dd0 ^ ((r & 7) << 3);
  const float* src = Kg + ((size_t)bh * NN + chunk * 64 + r) * ND + d0;
  float4 a = *reinterpret_cast<const float4*>(src);
  float4 c4 = *reinterpret_cast<const float4*>(src + 4);
  float f[8] = {a.x, a.y, a.z, a.w, c4.x, c4.y, c4.z, c4.w};
  s16x8 hi, lo;
#pragma unroll
  for (int j = 0; j < 8; ++j) {
    short h = f2bf(f[j]);
    hi[j] = h;
    lo[j] = f2bf(f[j] - bf2f(h));
  }
  *reinterpret_cast<s16x8*>(Khi + p0) = hi;
  *reinterpret_cast<s16x8*>(Klo + p0) = lo;
}

// ---------------- pre-kernel 2: V -> V^T bf16 [bh][d][k] -------------------
__global__ void pack_vt(const float* __restrict__ Vg, short* __restrict__ Vt) {
  __shared__ float tile[64 * 65];
  int bh = blockIdx.x >> 4;
  int kc = blockIdx.x & 15;
  int tid = threadIdx.x;
#pragma unroll
  for (int i = 0; i < 4; ++i) {
    int e = tid + i * 256;
    int k = e >> 4, d0 = (e & 15) * 4;
    const float* src = Vg + ((size_t)bh * NN + kc * 64 + k) * ND + d0;
    float4 v = *reinterpret_cast<const float4*>(src);
    float* dst = &tile[k * 65 + d0];
    dst[0] = v.x; dst[1] = v.y; dst[2] = v.z; dst[3] = v.w;
  }
  __syncthreads();
  {
    int d = tid >> 2;
    int kk = (tid & 3) * 16;
    s16x8 o0, o1;
#pragma unroll
    for (int j = 0; j < 8; ++j) o0[j] = f2bf(tile[(kk + j) * 65 + d]);
#pragma unroll
    for (int j = 0; j < 8; ++j) o1[j] = f2bf(tile[(kk + 8 + j) * 65 + d]);
    short* dst = Vt + ((size_t)bh * ND + d) * NN + kc * 64 + kk;
    *reinterpret_cast<s16x8*>(dst) = o0;
    *reinterpret_cast<s16x8*>(dst + 8) = o1;
  }
}

// ---------------- main fused kernel ---------------------------------------
__global__ __launch_bounds__(256, 3) void mrsa_main(
    const float* __restrict__ Qg, const float* __restrict__ Ag,
    const float* __restrict__ Wg, const short* __restrict__ Khi,
    const short* __restrict__ Klo, const short* __restrict__ Vt,
    float* __restrict__ outO, float* __restrict__ outW) {
  __shared__ short kbuf[16384];  // phase1: 2x(4KB hi|4KB lo); ph2/3: P bf16
  __shared__ float red0[16][4];
  __shared__ float red1[16][4];

  const int tid = threadIdx.x;
  const int lane = tid & 63;
  const int wv = tid >> 6;
  const int l4 = lane & 15;
  const int hi4 = lane >> 4;

  // Hybrid order: XCD x owns (b = x>>1, rb-half = x&1); within XCD
  // i = [rbo:3][ho:1][rbi:2][hi:3] -> A slices L2-resident across heads.
  const int x = blockIdx.x & 7;
  const int i = blockIdx.x >> 3;
  const int b = x >> 1;
  const int h = ((i >> 5) & 1) * 8 + (i & 7);
  const int rb = (x & 1) * 32 + ((i >> 6) << 2) + ((i >> 3) & 3);
  const int row0 = rb * 16;

  const size_t bh = (size_t)b * NH + h;
  const float* Qp = Qg + bh * (NN * ND);

  float wE[NT];
#pragma unroll
  for (int t = 0; t < NT; ++t) wE[t] = Wg[t * NH + h];

  const int k0 = hi4 * 8;  // MFMA k base within 32

  // Q fragments (hi/lo bf16 split); B-operand col = l4 -> Q row = row0+l4
  s16x8 qh[2], ql[2];
#pragma unroll
  for (int ks = 0; ks < 2; ++ks) {
    const float* qrow = Qp + (size_t)(row0 + l4) * ND + ks * 32 + k0;
#pragma unroll
    for (int j = 0; j < 8; ++j) {
      float f = qrow[j];
      short hb = f2bf(f);
      qh[ks][j] = hb;
      ql[ks][j] = f2bf(f - bf2f(hb));
    }
  }

  const int bcol = wv * 16 + l4;    // K row (score col m) within chunk
  const int bsw = (bcol & 7) << 3;  // K LDS swizzle for this row
  const size_t kbase = bh * 65536;

  // Swapped layout: thread owns S[q=l4][m = c*64 + wv*16 + hi4*4 + r].
  // Bias: A[t][b][row0+l4][c*64 + wv*16 + hi4*4 .. +3] -> one float4 per t.
  const int mbase = wv * 16 + hi4 * 4;
  const float* Ap[NT];
#pragma unroll
  for (int t = 0; t < NT; ++t)
    Ap[t] = Ag + ((size_t)t * NB + b) * (NN * NN) +
            (size_t)(row0 + l4) * NN + mbase;

  f32x4 sAcc[16];
  float4 aB4[2][NT];

#define STAGE_K(cc)                                                         \
  do {                                                                      \
    size_t g0 =                                                             \
        kbase + (size_t)(cc)*4096 + (size_t)wv * 1024 + (size_t)lane * 8;   \
    short* KH = &kbuf[((cc)&1) * 8192];                                     \
    short* KL = KH + 4096;                                                  \
    gload_lds16(Khi + g0, KH + wv * 1024);                                  \
    gload_lds16(Khi + g0 + 512, KH + wv * 1024 + 512);                      \
    gload_lds16(Klo + g0, KL + wv * 1024);                                  \
    gload_lds16(Klo + g0 + 512, KL + wv * 1024 + 512);                      \
  } while (0)

#define ISSUE_A(cc)                                                         \
  do {                                                                      \
    _Pragma("unroll") for (int t = 0; t < NT; ++t) {                        \
      aB4[(cc)&1][t] =                                                      \
          *reinterpret_cast<const float4*>(Ap[t] + (cc)*64);                \
    }                                                                       \
  } while (0)

  STAGE_K(0);
  ISSUE_A(0);

  // ============ Phase 1: biased S^T into registers ========================
#pragma unroll
  for (int c = 0; c < 16; ++c) {
    __syncthreads();  // K(c) DMA + A(c) loads drained
    if (c < 15) {
      STAGE_K(c + 1);
      ISSUE_A(c + 1);
    }
    const short* KH = &kbuf[(c & 1) * 8192];
    const short* KL = KH + 4096;
    s16x8 kh8[2], kl8[2];
#pragma unroll
    for (int ks = 0; ks < 2; ++ks) {
      int ph = bcol * 64 + ((ks * 32 + k0) ^ bsw);
      kh8[ks] = *reinterpret_cast<const s16x8*>(&KH[ph]);
      kl8[ks] = *reinterpret_cast<const s16x8*>(&KL[ph]);
    }
    f32x4 acc = {0.f, 0.f, 0.f, 0.f};
#pragma unroll
    for (int ks = 0; ks < 2; ++ks) {
      // SWAPPED: A-operand = K (rows = score cols m), B-operand = Q.
      acc = __builtin_amdgcn_mfma_f32_16x16x32_bf16(kh8[ks], qh[ks], acc, 0, 0, 0);
      acc = __builtin_amdgcn_mfma_f32_16x16x32_bf16(kl8[ks], qh[ks], acc, 0, 0, 0);
      acc = __builtin_amdgcn_mfma_f32_16x16x32_bf16(kh8[ks], ql[ks], acc, 0, 0, 0);
    }
    float4 a0 = aB4[c & 1][0], a1 = aB4[c & 1][1];
    float4 a2 = aB4[c & 1][2], a3 = aB4[c & 1][3];
    float b0 = wE[0] * a0.x + wE[1] * a1.x + wE[2] * a2.x + wE[3] * a3.x;
    float b1 = wE[0] * a0.y + wE[1] * a1.y + wE[2] * a2.y + wE[3] * a3.y;
    float b2 = wE[0] * a0.z + wE[1] * a1.z + wE[2] * a2.z + wE[3] * a3.z;
    float b3 = wE[0] * a0.w + wE[1] * a1.w + wE[2] * a2.w + wE[3] * a3.w;
    sAcc[c][0] = acc[0] * (1.f + b0) * 0.125f;
    sAcc[c][1] = acc[1] * (1.f + b1) * 0.125f;
    sAcc[c][2] = acc[2] * (1.f + b2) * 0.125f;
    sAcc[c][3] = acc[3] * (1.f + b3) * 0.125f;
  }

  // ============ Phase 2: softmax (row q = l4; 64 vals/thread) =============
  float m = sAcc[0][0];
#pragma unroll
  for (int c = 0; c < 16; ++c) {
#pragma unroll
    for (int r = 0; r < 4; ++r) m = fmaxf(m, sAcc[c][r]);
  }
  m = fmaxf(m, __shfl_xor(m, 16));
  m = fmaxf(m, __shfl_xor(m, 32));
  if (hi4 == 0) red0[l4][wv] = m;
  __syncthreads();
  float mfin, inv;
  {
    float4 v = *reinterpret_cast<const float4*>(&red0[l4][0]);
    mfin = fmaxf(fmaxf(v.x, v.y), fmaxf(v.z, v.w));
  }
  float s = 0.f;
#pragma unroll
  for (int c = 0; c < 16; ++c) {
#pragma unroll
    for (int r = 0; r < 4; ++r) {
      float e = __expf(sAcc[c][r] - mfin);
      sAcc[c][r] = e;
      s += e;
    }
  }
  s += __shfl_xor(s, 16);
  s += __shfl_xor(s, 32);
  if (hi4 == 0) red1[l4][wv] = s;
  __syncthreads();  // all waves past phase 1 -> safe to overwrite kbuf w/ P
  {
    float4 v = *reinterpret_cast<const float4*>(&red1[l4][0]);
    inv = 1.f / (v.x + v.y + v.z + v.w);
  }

  // ============ P pack (bf16 -> LDS [16][1024], xor-swizzled) =============
  {
    const int prow = l4 * 1024;
    const int swz = (l4 & 7) << 3;
#pragma unroll
    for (int c = 0; c < 16; ++c) {
      s16x4 p;
      p[0] = f2bf(sAcc[c][0] * inv);
      p[1] = f2bf(sAcc[c][1] * inv);
      p[2] = f2bf(sAcc[c][2] * inv);
      p[3] = f2bf(sAcc[c][3] * inv);
      *reinterpret_cast<s16x4*>(&kbuf[prow + ((c * 64 + mbase) ^ swz)]) = p;
    }
  }
  __syncthreads();

  // ============ Phase 3: out = P @ V via V^T bf16 =========================
  {
    f32x4 acc = {0.f, 0.f, 0.f, 0.f};
    const int dcol = wv * 16 + l4;
    const int abase = l4 * 1024;
    const int asw = (l4 & 7) << 3;
    const short* vtp = Vt + (bh * ND + (size_t)dcol) * NN;
#pragma unroll 8
    for (int kk = 0; kk < 32; ++kk) {
      int kb = kk * 32 + k0;
      s16x8 af = *reinterpret_cast<const s16x8*>(&kbuf[abase + (kb ^ asw)]);
      s16x8 bfv = *reinterpret_cast<const s16x8*>(&vtp[kb]);
      acc = __builtin_amdgcn_mfma_f32_16x16x32_bf16(af, bfv, acc, 0, 0, 0);
    }
#pragma unroll
    for (int r = 0; r < 4; ++r) {
      __builtin_nontemporal_store(
          acc[r], &outO[(bh * NN + (size_t)(row0 + hi4 * 4 + r)) * ND + dcol]);
    }
  }

  // ============ W write: coalesced float4 nt-stores from P LDS ============
#pragma unroll
  for (int rr = 0; rr < 4; ++rr) {
    const int row = wv * 4 + rr;
    const int sw8 = (row & 7) << 3;
    float* gw = outW + ((bh * NN + (size_t)(row0 + row)) << 10);
    const int prow = row * 1024;
#pragma unroll
    for (int i2 = 0; i2 < 4; ++i2) {
      int gcol = lane * 4 + i2 * 256;
      s16x4 p4 = *reinterpret_cast<const s16x4*>(&kbuf[prow + (gcol ^ sw8)]);
      f32x4 w4;
      w4[0] = bf2f(p4[0]);
      w4[1] = bf2f(p4[1]);
      w4[2] = bf2f(p4[2]);
      w4[3] = bf2f(p4[3]);
      __builtin_nontemporal_store(w4, reinterpret_cast<f32x4*>(&gw[gcol]));
    }
  }
#undef STAGE_K
#undef ISSUE_A
}

// ---------------- fallback (round-1 kernel, no workspace) ------------------
__global__ __launch_bounds__(256, 2) void mrsa_fused(
    const float* __restrict__ Qg, const float* __restrict__ Kg,
    const float* __restrict__ Vg, const float* __restrict__ Ag,
    const float* __restrict__ Wg, float* __restrict__ outO,
    float* __restrict__ outW) {
  __shared__ short KsHi[64 * 64];
  __shared__ short KsLo[64 * 64];
  __shared__ float Ss[16 * 1024];
  const int tid = threadIdx.x;
  const int lane = tid & 63;
  const int wv = tid >> 6;
  const int rb = blockIdx.x;
  const int h = blockIdx.y;
  const int b = blockIdx.z;
  const int row0 = rb * 16;
  const size_t bh = (size_t)b * NH + h;
  const float* Qp = Qg + bh * (NN * ND);
  const float* Kp = Kg + bh * (NN * ND);
  const float* Vp = Vg + bh * (NN * ND);
  float wE[NT];
#pragma unroll
  for (int t = 0; t < NT; ++t) wE[t] = Wg[t * NH + h];
  const int arow = lane & 15;
  const int k0 = (lane >> 4) * 8;
  s16x8 qh[2], ql[2];
#pragma unroll
  for (int ks = 0; ks < 2; ++ks) {
    const float* qrow = Qp + (size_t)(row0 + arow) * ND + ks * 32 + k0;
#pragma unroll
    for (int j = 0; j < 8; ++j) {
      float f = qrow[j];
      short hi = f2bf(f);
      qh[ks][j] = hi;
      ql[ks][j] = f2bf(f - bf2f(hi));
    }
  }
  const int bcol = wv * 16 + (lane & 15);
  const int bsw = (bcol & 7) << 3;
  for (int c = 0; c < 16; ++c) {
#pragma unroll
    for (int i = 0; i < 4; ++i) {
      int e4 = tid + i * 256;
      int r = e4 >> 4;
      int d0 = (e4 & 15) * 4;
      float4 kv = *reinterpret_cast<const float4*>(
          Kp + (size_t)(c * 64 + r) * ND + d0);
      float kf[4];
      kf[0] = kv.x; kf[1] = kv.y; kf[2] = kv.z; kf[3] = kv.w;
      s16x4 hi4, lo4;
#pragma unroll
      for (int j = 0; j < 4; ++j) {
        short hi = f2bf(kf[j]);
        hi4[j] = hi;
        lo4[j] = f2bf(kf[j] - bf2f(hi));
      }
      int sw = r * 64 + (d0 ^ ((r & 7) << 3));
      *reinterpret_cast<s16x4*>(&KsHi[sw]) = hi4;
      *reinterpret_cast<s16x4*>(&KsLo[sw]) = lo4;
    }
    __syncthreads();
    f32x4 acc = {0.f, 0.f, 0.f, 0.f};
#pragma unroll
    for (int ks = 0; ks < 2; ++ks) {
      int kb = ks * 32 + k0;
      int ph = bcol * 64 + (kb ^ bsw);
      s16x8 kh8 = *reinterpret_cast<const s16x8*>(&KsHi[ph]);
      s16x8 kl8 = *reinterpret_cast<const s16x8*>(&KsLo[ph]);
      acc = __builtin_amdgcn_mfma_f32_16x16x32_bf16(qh[ks], kh8, acc, 0, 0, 0);
      acc = __builtin_amdgcn_mfma_f32_16x16x32_bf16(qh[ks], kl8, acc, 0, 0, 0);
      acc = __builtin_amdgcn_mfma_f32_16x16x32_bf16(ql[ks], kh8, acc, 0, 0, 0);
    }
    int gcol = c * 64 + bcol;
#pragma unroll
    for (int r = 0; r < 4; ++r) {
      int lrow = (lane >> 4) * 4 + r;
      int grow = row0 + lrow;
      float bias = 0.f;
#pragma unroll
      for (int t = 0; t < NT; ++t)
        bias += wE[t] *
                Ag[((size_t)t * NB + b) * (NN * NN) + (size_t)grow * NN + gcol];
      Ss[lrow * 1024 + (gcol ^ ((lrow & 7) << 3))] =
          acc[r] * (1.f + bias) * 0.125f;
    }
    __syncthreads();
  }
#pragma unroll
  for (int rr = 0; rr < 4; ++rr) {
    int lrow = wv * 4 + rr;
    float* srow = &Ss[lrow * 1024];
    int sw = (lrow & 7) << 3;
    float m = -3.4e38f;
#pragma unroll
    for (int i = 0; i < 16; ++i) m = fmaxf(m, srow[i * 64 + lane]);
#pragma unroll
    for (int off = 32; off; off >>= 1) m = fmaxf(m, __shfl_xor(m, off));
    float ev[16];
    float lsum = 0.f;
#pragma unroll
    for (int i = 0; i < 16; ++i) {
      float e = __expf(srow[i * 64 + lane] - m);
      ev[i] = e;
      lsum += e;
    }
#pragma unroll
    for (int off = 32; off; off >>= 1) lsum += __shfl_xor(lsum, off);
    float inv = 1.f / lsum;
    float* gw = outW + (bh * NN + (size_t)(row0 + lrow)) * NN;
#pragma unroll
    for (int i = 0; i < 16; ++i) {
      float w = ev[i] * inv;
      int p = i * 64 + lane;
      srow[p] = w;
      gw[p ^ sw] = w;
    }
  }
  __syncthreads();
  {
    f32x4 acc = {0.f, 0.f, 0.f, 0.f};
    const int dcol = wv * 16 + (lane & 15);
    const int asw = (arow & 7) << 3;
    const float* srow = &Ss[arow * 1024];
#pragma unroll 2
    for (int kk = 0; kk < 32; ++kk) {
      int kb = kk * 32 + k0;
      int ph = kb ^ asw;
      float4 a0 = *reinterpret_cast<const float4*>(&srow[ph]);
      float4 a1 = *reinterpret_cast<const float4*>(&srow[ph + 4]);
      s16x8 af, bfv;
      af[0] = f2bf(a0.x); af[1] = f2bf(a0.y);
      af[2] = f2bf(a0.z); af[3] = f2bf(a0.w);
      af[4] = f2bf(a1.x); af[5] = f2bf(a1.y);
      af[6] = f2bf(a1.z); af[7] = f2bf(a1.w);
      const float* vcol = Vp + (size_t)kb * ND + dcol;
#pragma unroll
      for (int j = 0; j < 8; ++j) bfv[j] = f2bf(vcol[j * ND]);
      acc = __builtin_amdgcn_mfma_f32_16x16x32_bf16(af, bfv, acc, 0, 0, 0);
    }
#pragma unroll
    for (int r = 0; r < 4; ++r) {
      int lrow = (lane >> 4) * 4 + r;
      outO[(bh * NN + (size_t)(row0 + lrow)) * ND + dcol] = acc[r];
    }
  }
}

extern "C" void kernel_launch(void* const* d_in, const int* in_sizes, int n_in,
                              void* d_out, int out_size, void* d_ws,
                              size_t ws_size, hipStream_t stream) {
  const float* Q = (const float*)d_in[0];
  const float* K = (const float*)d_in[1];
  const float* V = (const float*)d_in[2];
  const float* A = (const float*)d_in[3];
  const float* wE = (const float*)d_in[4];
  float* out = (float*)d_out;
  float* outW = out + (size_t)NB * NH * NN * ND;

  const size_t nElem = (size_t)NB * NH * NN * ND;  // 4194304
  const size_t needK = 3 * nElem * sizeof(short);  // Khi + Klo + Vt (24MB)
  if (ws_size >= needK) {
    short* Khi = (short*)d_ws;
    short* Klo = Khi + nElem;
    short* Vt = Klo + nElem;
    hipLaunchKernelGGL(pack_k, dim3(2048), dim3(256), 0, stream, K, Khi, Klo);
    hipLaunchKernelGGL(pack_vt, dim3(NB * NH * 16), dim3(256), 0, stream, V,
                       Vt);
    hipLaunchKernelGGL(mrsa_main, dim3(4096), dim3(256), 0, stream, Q, A, wE,
                       Khi, Klo, Vt, out, outW);
  } else {
    dim3 grid(NN / 16, NH, NB);
    hipLaunchKernelGGL(mrsa_fused, grid, dim3(256), 0, stream, Q, K, V, A, wE,
                       out, outW);
  }
}

// Round 18
// 185.943 us; speedup vs baseline: 1.2857x; 1.2857x over previous
//
#include <hip/hip_runtime.h>

// MultiRelationalSelfAttention: B=4,H=16,N=1024,D=64,T=4
//   S = Q@K^T * (1 + sum_t w[t,h]*A[t,b]) / 8 ; W = softmax(S); out = W@V
// Outputs (concat): out [B,H,N,D] f32, then attn_weight [B,H,N,N] f32.
//
// FINAL (r18 = r13 verbatim, best: 185.6us bench).
//  Structure: per (b,h,16-row block), 256 thr / 4 waves, 3 blocks/CU.
//  - K pre-packed bf16 hi/lo (precision: 3-MFMA hi/lo QK^T), DMA-swizzled
//    so global_load_lds width=16 staging lands XOR-swizzled in LDS.
//  - V pre-transposed to V^T bf16 -> PV B-fragment = one 16B load.
//  - Hybrid XCD block order: A slices L2-resident across heads (FETCH
//    520 -> 219MB vs naive order).
//  - S in registers; no-LDS-roundtrip softmax (16-lane shfl + tiny LDS).
//  - W written AFTER PV from the P LDS buffer as coalesced float4
//    nt-stores (bf16-rounded, err<=0.004 << 0.078 threshold).
//  Verified dead ends (r14-r17): removing per-chunk barriers, 2-deep K
//  prefetch, direct-to-register K, transposed-MFMA A-gather — all
//  neutral or worse; the compiler's conservative vmcnt handling around
//  LDS-DMA makes deeper source-level pipelining ineffective here.

#define NB 4
#define NH 16
#define NN 1024
#define ND 64
#define NT 4

typedef short s16x4 __attribute__((ext_vector_type(4)));
typedef short s16x8 __attribute__((ext_vector_type(8)));
typedef float f32x4 __attribute__((ext_vector_type(4)));

__device__ __forceinline__ short f2bf(float f) {
  return __builtin_bit_cast(short, (__bf16)f);
}
__device__ __forceinline__ float bf2f(short s) {
  return __builtin_bit_cast(float, ((unsigned)(unsigned short)s) << 16);
}

__device__ __forceinline__ void gload_lds16(const void* g, void* l) {
  __builtin_amdgcn_global_load_lds(
      (const __attribute__((address_space(1))) unsigned int*)g,
      (__attribute__((address_space(3))) unsigned int*)l, 16, 0, 0);
}

// ---------------- pre-kernel 1: K -> bf16 hi/lo, DMA-swizzled --------------
__global__ void pack_k(const float* __restrict__ Kg, short* __restrict__ Khi,
                       short* __restrict__ Klo) {
  int t = blockIdx.x * 256 + threadIdx.x;
  int p0 = t * 8;
  int bh = p0 >> 16;
  int rem = p0 & 65535;
  int chunk = rem >> 12;
  int e = rem & 4095;
  int r = e >> 6;
  int dd0 = e & 63;
  int d0 = dd0 ^ ((r & 7) << 3);
  const float* src = Kg + ((size_t)bh * NN + chunk * 64 + r) * ND + d0;
  float4 a = *reinterpret_cast<const float4*>(src);
  float4 c4 = *reinterpret_cast<const float4*>(src + 4);
  float f[8] = {a.x, a.y, a.z, a.w, c4.x, c4.y, c4.z, c4.w};
  s16x8 hi, lo;
#pragma unroll
  for (int j = 0; j < 8; ++j) {
    short h = f2bf(f[j]);
    hi[j] = h;
    lo[j] = f2bf(f[j] - bf2f(h));
  }
  *reinterpret_cast<s16x8*>(Khi + p0) = hi;
  *reinterpret_cast<s16x8*>(Klo + p0) = lo;
}

// ---------------- pre-kernel 2: V -> V^T bf16 [bh][d][k] -------------------
__global__ void pack_vt(const float* __restrict__ Vg, short* __restrict__ Vt) {
  __shared__ float tile[64 * 65];
  int bh = blockIdx.x >> 4;
  int kc = blockIdx.x & 15;
  int tid = threadIdx.x;
#pragma unroll
  for (int i = 0; i < 4; ++i) {
    int e = tid + i * 256;
    int k = e >> 4, d0 = (e & 15) * 4;
    const float* src = Vg + ((size_t)bh * NN + kc * 64 + k) * ND + d0;
    float4 v = *reinterpret_cast<const float4*>(src);
    float* dst = &tile[k * 65 + d0];
    dst[0] = v.x; dst[1] = v.y; dst[2] = v.z; dst[3] = v.w;
  }
  __syncthreads();
  {
    int d = tid >> 2;
    int kk = (tid & 3) * 16;
    s16x8 o0, o1;
#pragma unroll
    for (int j = 0; j < 8; ++j) o0[j] = f2bf(tile[(kk + j) * 65 + d]);
#pragma unroll
    for (int j = 0; j < 8; ++j) o1[j] = f2bf(tile[(kk + 8 + j) * 65 + d]);
    short* dst = Vt + ((size_t)bh * ND + d) * NN + kc * 64 + kk;
    *reinterpret_cast<s16x8*>(dst) = o0;
    *reinterpret_cast<s16x8*>(dst + 8) = o1;
  }
}

// ---------------- main fused kernel ---------------------------------------
__global__ __launch_bounds__(256, 3) void mrsa_main(
    const float* __restrict__ Qg, const float* __restrict__ Ag,
    const float* __restrict__ Wg, const short* __restrict__ Khi,
    const short* __restrict__ Klo, const short* __restrict__ Vt,
    float* __restrict__ outO, float* __restrict__ outW) {
  __shared__ short kbuf[16384];  // phase1: 2x(4KB hi|4KB lo); ph2/3: P bf16
  __shared__ float red0[16][4];
  __shared__ float red1[16][4];

  const int tid = threadIdx.x;
  const int lane = tid & 63;
  const int wv = tid >> 6;
  const int l4 = lane & 15;
  const int hi4 = lane >> 4;

  // Hybrid order: XCD x owns (b = x>>1, rb-half = x&1); within XCD
  // i = [rbo:3][ho:1][rbi:2][hi:3] -> A slices L2-resident across heads.
  const int x = blockIdx.x & 7;
  const int i = blockIdx.x >> 3;
  const int b = x >> 1;
  const int h = ((i >> 5) & 1) * 8 + (i & 7);
  const int rb = (x & 1) * 32 + ((i >> 6) << 2) + ((i >> 3) & 3);
  const int row0 = rb * 16;

  const size_t bh = (size_t)b * NH + h;
  const float* Qp = Qg + bh * (NN * ND);

  float wE[NT];
#pragma unroll
  for (int t = 0; t < NT; ++t) wE[t] = Wg[t * NH + h];

  const int k0 = hi4 * 8;  // MFMA k base within 32

  // Q fragments (hi/lo bf16 split), A-frag row = l4
  s16x8 qh[2], ql[2];
#pragma unroll
  for (int ks = 0; ks < 2; ++ks) {
    const float* qrow = Qp + (size_t)(row0 + l4) * ND + ks * 32 + k0;
#pragma unroll
    for (int j = 0; j < 8; ++j) {
      float f = qrow[j];
      short hb = f2bf(f);
      qh[ks][j] = hb;
      ql[ks][j] = f2bf(f - bf2f(hb));
    }
  }

  const int bcol = wv * 16 + l4;    // score col within 64-col chunk
  const int bsw = (bcol & 7) << 3;  // K LDS swizzle for this col
  const size_t kbase = bh * 65536;

  const float* Ap[NT];
#pragma unroll
  for (int t = 0; t < NT; ++t)
    Ap[t] = Ag + ((size_t)t * NB + b) * (NN * NN) +
            (size_t)(row0 + hi4 * 4) * NN + bcol;

  f32x4 sAcc[16];
  float aBuf[2][NT][4];

#define STAGE_K(cc)                                                         \
  do {                                                                      \
    size_t g0 =                                                             \
        kbase + (size_t)(cc)*4096 + (size_t)wv * 1024 + (size_t)lane * 8;   \
    short* KH = &kbuf[((cc)&1) * 8192];                                     \
    short* KL = KH + 4096;                                                  \
    gload_lds16(Khi + g0, KH + wv * 1024);                                  \
    gload_lds16(Khi + g0 + 512, KH + wv * 1024 + 512);                      \
    gload_lds16(Klo + g0, KL + wv * 1024);                                  \
    gload_lds16(Klo + g0 + 512, KL + wv * 1024 + 512);                      \
  } while (0)

#define ISSUE_A(cc)                                                         \
  do {                                                                      \
    _Pragma("unroll") for (int t = 0; t < NT; ++t) {                        \
      _Pragma("unroll") for (int r = 0; r < 4; ++r) {                       \
        aBuf[(cc)&1][t][r] = Ap[t][r * NN + (cc)*64];                       \
      }                                                                     \
    }                                                                       \
  } while (0)

  STAGE_K(0);
  ISSUE_A(0);

  // ============ Phase 1: biased S into registers ==========================
#pragma unroll
  for (int c = 0; c < 16; ++c) {
    __syncthreads();  // K(c) DMA + A(c) loads drained
    if (c < 15) {
      STAGE_K(c + 1);
      ISSUE_A(c + 1);
    }
    const short* KH = &kbuf[(c & 1) * 8192];
    const short* KL = KH + 4096;
    s16x8 kh8[2], kl8[2];
#pragma unroll
    for (int ks = 0; ks < 2; ++ks) {
      int ph = bcol * 64 + ((ks * 32 + k0) ^ bsw);
      kh8[ks] = *reinterpret_cast<const s16x8*>(&KH[ph]);
      kl8[ks] = *reinterpret_cast<const s16x8*>(&KL[ph]);
    }
    f32x4 acc = {0.f, 0.f, 0.f, 0.f};
#pragma unroll
    for (int ks = 0; ks < 2; ++ks) {
      acc = __builtin_amdgcn_mfma_f32_16x16x32_bf16(qh[ks], kh8[ks], acc, 0, 0, 0);
      acc = __builtin_amdgcn_mfma_f32_16x16x32_bf16(qh[ks], kl8[ks], acc, 0, 0, 0);
      acc = __builtin_amdgcn_mfma_f32_16x16x32_bf16(ql[ks], kh8[ks], acc, 0, 0, 0);
    }
#pragma unroll
    for (int r = 0; r < 4; ++r) {
      float bias = wE[0] * aBuf[c & 1][0][r] + wE[1] * aBuf[c & 1][1][r] +
                   wE[2] * aBuf[c & 1][2][r] + wE[3] * aBuf[c & 1][3][r];
      sAcc[c][r] = acc[r] * (1.f + bias) * 0.125f;
    }
  }

  // ============ Phase 2: softmax in registers =============================
  float mr[4];
#pragma unroll
  for (int r = 0; r < 4; ++r) {
    float m = sAcc[0][r];
#pragma unroll
    for (int c = 1; c < 16; ++c) m = fmaxf(m, sAcc[c][r]);
    mr[r] = m;
  }
#pragma unroll
  for (int off = 8; off >= 1; off >>= 1) {
#pragma unroll
    for (int r = 0; r < 4; ++r) mr[r] = fmaxf(mr[r], __shfl_xor(mr[r], off));
  }
  if (l4 == 0) {
#pragma unroll
    for (int r = 0; r < 4; ++r) red0[hi4 * 4 + r][wv] = mr[r];
  }
  __syncthreads();
  float mfin[4], inv[4];
#pragma unroll
  for (int r = 0; r < 4; ++r) {
    float4 v = *reinterpret_cast<const float4*>(&red0[hi4 * 4 + r][0]);
    mfin[r] = fmaxf(fmaxf(v.x, v.y), fmaxf(v.z, v.w));
  }
  float sr[4];
#pragma unroll
  for (int r = 0; r < 4; ++r) {
    float s = 0.f;
#pragma unroll
    for (int c = 0; c < 16; ++c) {
      float e = __expf(sAcc[c][r] - mfin[r]);
      sAcc[c][r] = e;
      s += e;
    }
    sr[r] = s;
  }
#pragma unroll
  for (int off = 8; off >= 1; off >>= 1) {
#pragma unroll
    for (int r = 0; r < 4; ++r) sr[r] += __shfl_xor(sr[r], off);
  }
  if (l4 == 0) {
#pragma unroll
    for (int r = 0; r < 4; ++r) red1[hi4 * 4 + r][wv] = sr[r];
  }
  __syncthreads();  // all waves done with K LDS -> safe to write P
#pragma unroll
  for (int r = 0; r < 4; ++r) {
    float4 v = *reinterpret_cast<const float4*>(&red1[hi4 * 4 + r][0]);
    inv[r] = 1.f / (v.x + v.y + v.z + v.w);
  }

  // ============ P pack (bf16 -> LDS [16][1024], xor-swizzled) =============
#pragma unroll
  for (int r = 0; r < 4; ++r) {
    const int lrow = hi4 * 4 + r;
    const int prow = lrow * 1024;
    const int swc = bcol ^ ((lrow & 7) << 3);
#pragma unroll
    for (int c = 0; c < 16; ++c) {
      kbuf[prow + c * 64 + swc] = f2bf(sAcc[c][r] * inv[r]);
    }
  }
  __syncthreads();

  // ============ Phase 3: out = P @ V via V^T bf16 =========================
  {
    f32x4 acc = {0.f, 0.f, 0.f, 0.f};
    const int dcol = bcol;
    const int abase = l4 * 1024;
    const int asw = (l4 & 7) << 3;
    const short* vtp = Vt + (bh * ND + (size_t)dcol) * NN;
#pragma unroll 8
    for (int kk = 0; kk < 32; ++kk) {
      int kb = kk * 32 + k0;
      s16x8 af = *reinterpret_cast<const s16x8*>(&kbuf[abase + (kb ^ asw)]);
      s16x8 bfv = *reinterpret_cast<const s16x8*>(&vtp[kb]);
      acc = __builtin_amdgcn_mfma_f32_16x16x32_bf16(af, bfv, acc, 0, 0, 0);
    }
#pragma unroll
    for (int r = 0; r < 4; ++r) {
      __builtin_nontemporal_store(
          acc[r], &outO[(bh * NN + (size_t)(row0 + hi4 * 4 + r)) * ND + dcol]);
    }
  }

  // ============ W write: coalesced float4 nt-stores from P LDS ============
#pragma unroll
  for (int rr = 0; rr < 4; ++rr) {
    const int row = wv * 4 + rr;
    const int sw8 = (row & 7) << 3;
    float* gw = outW + ((bh * NN + (size_t)(row0 + row)) << 10);
    const int prow = row * 1024;
#pragma unroll
    for (int i2 = 0; i2 < 4; ++i2) {
      int gcol = lane * 4 + i2 * 256;
      s16x4 p4 = *reinterpret_cast<const s16x4*>(&kbuf[prow + (gcol ^ sw8)]);
      f32x4 w4;
      w4[0] = bf2f(p4[0]);
      w4[1] = bf2f(p4[1]);
      w4[2] = bf2f(p4[2]);
      w4[3] = bf2f(p4[3]);
      __builtin_nontemporal_store(w4, reinterpret_cast<f32x4*>(&gw[gcol]));
    }
  }
#undef STAGE_K
#undef ISSUE_A
}

// ---------------- fallback (round-1 kernel, no workspace) ------------------
__global__ __launch_bounds__(256, 2) void mrsa_fused(
    const float* __restrict__ Qg, const float* __restrict__ Kg,
    const float* __restrict__ Vg, const float* __restrict__ Ag,
    const float* __restrict__ Wg, float* __restrict__ outO,
    float* __restrict__ outW) {
  __shared__ short KsHi[64 * 64];
  __shared__ short KsLo[64 * 64];
  __shared__ float Ss[16 * 1024];
  const int tid = threadIdx.x;
  const int lane = tid & 63;
  const int wv = tid >> 6;
  const int rb = blockIdx.x;
  const int h = blockIdx.y;
  const int b = blockIdx.z;
  const int row0 = rb * 16;
  const size_t bh = (size_t)b * NH + h;
  const float* Qp = Qg + bh * (NN * ND);
  const float* Kp = Kg + bh * (NN * ND);
  const float* Vp = Vg + bh * (NN * ND);
  float wE[NT];
#pragma unroll
  for (int t = 0; t < NT; ++t) wE[t] = Wg[t * NH + h];
  const int arow = lane & 15;
  const int k0 = (lane >> 4) * 8;
  s16x8 qh[2], ql[2];
#pragma unroll
  for (int ks = 0; ks < 2; ++ks) {
    const float* qrow = Qp + (size_t)(row0 + arow) * ND + ks * 32 + k0;
#pragma unroll
    for (int j = 0; j < 8; ++j) {
      float f = qrow[j];
      short hi = f2bf(f);
      qh[ks][j] = hi;
      ql[ks][j] = f2bf(f - bf2f(hi));
    }
  }
  const int bcol = wv * 16 + (lane & 15);
  const int bsw = (bcol & 7) << 3;
  for (int c = 0; c < 16; ++c) {
#pragma unroll
    for (int i = 0; i < 4; ++i) {
      int e4 = tid + i * 256;
      int r = e4 >> 4;
      int d0 = (e4 & 15) * 4;
      float4 kv = *reinterpret_cast<const float4*>(
          Kp + (size_t)(c * 64 + r) * ND + d0);
      float kf[4];
      kf[0] = kv.x; kf[1] = kv.y; kf[2] = kv.z; kf[3] = kv.w;
      s16x4 hi4, lo4;
#pragma unroll
      for (int j = 0; j < 4; ++j) {
        short hi = f2bf(kf[j]);
        hi4[j] = hi;
        lo4[j] = f2bf(kf[j] - bf2f(hi));
      }
      int sw = r * 64 + (d0 ^ ((r & 7) << 3));
      *reinterpret_cast<s16x4*>(&KsHi[sw]) = hi4;
      *reinterpret_cast<s16x4*>(&KsLo[sw]) = lo4;
    }
    __syncthreads();
    f32x4 acc = {0.f, 0.f, 0.f, 0.f};
#pragma unroll
    for (int ks = 0; ks < 2; ++ks) {
      int kb = ks * 32 + k0;
      int ph = bcol * 64 + (kb ^ bsw);
      s16x8 kh8 = *reinterpret_cast<const s16x8*>(&KsHi[ph]);
      s16x8 kl8 = *reinterpret_cast<const s16x8*>(&KsLo[ph]);
      acc = __builtin_amdgcn_mfma_f32_16x16x32_bf16(qh[ks], kh8, acc, 0, 0, 0);
      acc = __builtin_amdgcn_mfma_f32_16x16x32_bf16(qh[ks], kl8, acc, 0, 0, 0);
      acc = __builtin_amdgcn_mfma_f32_16x16x32_bf16(ql[ks], kh8, acc, 0, 0, 0);
    }
    int gcol = c * 64 + bcol;
#pragma unroll
    for (int r = 0; r < 4; ++r) {
      int lrow = (lane >> 4) * 4 + r;
      int grow = row0 + lrow;
      float bias = 0.f;
#pragma unroll
      for (int t = 0; t < NT; ++t)
        bias += wE[t] *
                Ag[((size_t)t * NB + b) * (NN * NN) + (size_t)grow * NN + gcol];
      Ss[lrow * 1024 + (gcol ^ ((lrow & 7) << 3))] =
          acc[r] * (1.f + bias) * 0.125f;
    }
    __syncthreads();
  }
#pragma unroll
  for (int rr = 0; rr < 4; ++rr) {
    int lrow = wv * 4 + rr;
    float* srow = &Ss[lrow * 1024];
    int sw = (lrow & 7) << 3;
    float m = -3.4e38f;
#pragma unroll
    for (int i = 0; i < 16; ++i) m = fmaxf(m, srow[i * 64 + lane]);
#pragma unroll
    for (int off = 32; off; off >>= 1) m = fmaxf(m, __shfl_xor(m, off));
    float ev[16];
    float lsum = 0.f;
#pragma unroll
    for (int i = 0; i < 16; ++i) {
      float e = __expf(srow[i * 64 + lane] - m);
      ev[i] = e;
      lsum += e;
    }
#pragma unroll
    for (int off = 32; off; off >>= 1) lsum += __shfl_xor(lsum, off);
    float inv = 1.f / lsum;
    float* gw = outW + (bh * NN + (size_t)(row0 + lrow)) * NN;
#pragma unroll
    for (int i = 0; i < 16; ++i) {
      float w = ev[i] * inv;
      int p = i * 64 + lane;
      srow[p] = w;
      gw[p ^ sw] = w;
    }
  }
  __syncthreads();
  {
    f32x4 acc = {0.f, 0.f, 0.f, 0.f};
    const int dcol = wv * 16 + (lane & 15);
    const int asw = (arow & 7) << 3;
    const float* srow = &Ss[arow * 1024];
#pragma unroll 2
    for (int kk = 0; kk < 32; ++kk) {
      int kb = kk * 32 + k0;
      int ph = kb ^ asw;
      float4 a0 = *reinterpret_cast<const float4*>(&srow[ph]);
      float4 a1 = *reinterpret_cast<const float4*>(&srow[ph + 4]);
      s16x8 af, bfv;
      af[0] = f2bf(a0.x); af[1] = f2bf(a0.y);
      af[2] = f2bf(a0.z); af[3] = f2bf(a0.w);
      af[4] = f2bf(a1.x); af[5] = f2bf(a1.y);
      af[6] = f2bf(a1.z); af[7] = f2bf(a1.w);
      const float* vcol = Vp + (size_t)kb * ND + dcol;
#pragma unroll
      for (int j = 0; j < 8; ++j) bfv[j] = f2bf(vcol[j * ND]);
      acc = __builtin_amdgcn_mfma_f32_16x16x32_bf16(af, bfv, acc, 0, 0, 0);
    }
#pragma unroll
    for (int r = 0; r < 4; ++r) {
      int lrow = (lane >> 4) * 4 + r;
      outO[(bh * NN + (size_t)(row0 + lrow)) * ND + dcol] = acc[r];
    }
  }
}

extern "C" void kernel_launch(void* const* d_in, const int* in_sizes, int n_in,
                              void* d_out, int out_size, void* d_ws,
                              size_t ws_size, hipStream_t stream) {
  const float* Q = (const float*)d_in[0];
  const float* K = (const float*)d_in[1];
  const float* V = (const float*)d_in[2];
  const float* A = (const float*)d_in[3];
  const float* wE = (const float*)d_in[4];
  float* out = (float*)d_out;
  float* outW = out + (size_t)NB * NH * NN * ND;

  const size_t nElem = (size_t)NB * NH * NN * ND;  // 4194304
  const size_t needK = 3 * nElem * sizeof(short);  // Khi + Klo + Vt (24MB)
  if (ws_size >= needK) {
    short* Khi = (short*)d_ws;
    short* Klo = Khi + nElem;
    short* Vt = Klo + nElem;
    hipLaunchKernelGGL(pack_k, dim3(2048), dim3(256), 0, stream, K, Khi, Klo);
    hipLaunchKernelGGL(pack_vt, dim3(NB * NH * 16), dim3(256), 0, stream, V,
                       Vt);
    hipLaunchKernelGGL(mrsa_main, dim3(4096), dim3(256), 0, stream, Q, A, wE,
                       Khi, Klo, Vt, out, outW);
  } else {
    dim3 grid(NN / 16, NH, NB);
    hipLaunchKernelGGL(mrsa_fused, grid, dim3(256), 0, stream, Q, K, V, A, wE,
                       out, outW);
  }
}

// Round 19
// 184.525 us; speedup vs baseline: 1.2956x; 1.0077x over previous
//
#include <hip/hip_runtime.h>

// MultiRelationalSelfAttention: B=4,H=16,N=1024,D=64,T=4
//   S = Q@K^T * (1 + sum_t w[t,h]*A[t,b]) / 8 ; W = softmax(S); out = W@V
// Outputs (concat): out [B,H,N,D] f32, then attn_weight [B,H,N,N] f32.
//
// FINAL (r19 = r13 main kernel + merged pack pre-kernel).
//  Main-kernel structure (best measured, 185.6-185.9us bench):
//  - per (b,h,16-row block), 256 thr / 4 waves, 3 blocks/CU.
//  - K pre-packed bf16 hi/lo (3-MFMA hi/lo QK^T for precision), laid out
//    so global_load_lds width=16 staging lands XOR-swizzled in LDS.
//  - V pre-transposed to V^T bf16 -> PV B-fragment = one 16B load.
//  - Hybrid XCD block order: A slices L2-resident across heads
//    (FETCH 520 -> 219MB vs naive order).
//  - S in registers; register softmax (16-lane shfl + tiny LDS reduce).
//  - W written AFTER PV from the P LDS buffer as coalesced float4
//    nt-stores (bf16-rounded, err <= 0.004 << 0.078 threshold).
//  r19 change: pack_k + pack_vt fused into ONE 3072-block launch
//  (independent work; removes one dispatch-boundary drain ~5us).
//  Verified dead ends (r14-r17): barrier removal, 2-deep prefetch,
//  direct-to-register K, transposed-MFMA A-gather — all neutral/worse.

#define NB 4
#define NH 16
#define NN 1024
#define ND 64
#define NT 4

typedef short s16x4 __attribute__((ext_vector_type(4)));
typedef short s16x8 __attribute__((ext_vector_type(8)));
typedef float f32x4 __attribute__((ext_vector_type(4)));

__device__ __forceinline__ short f2bf(float f) {
  return __builtin_bit_cast(short, (__bf16)f);
}
__device__ __forceinline__ float bf2f(short s) {
  return __builtin_bit_cast(float, ((unsigned)(unsigned short)s) << 16);
}

__device__ __forceinline__ void gload_lds16(const void* g, void* l) {
  __builtin_amdgcn_global_load_lds(
      (const __attribute__((address_space(1))) unsigned int*)g,
      (__attribute__((address_space(3))) unsigned int*)l, 16, 0, 0);
}

// ------- merged pre-kernel: blocks [0,2048) pack K; [2048,3072) pack V^T ---
__global__ void pack_kv(const float* __restrict__ Kg,
                        const float* __restrict__ Vg,
                        short* __restrict__ Khi, short* __restrict__ Klo,
                        short* __restrict__ Vt) {
  __shared__ float tile[64 * 65];  // used by V^T path only
  const int tid = threadIdx.x;
  if (blockIdx.x < 2048) {
    // ---- K -> bf16 hi/lo, DMA-swizzled chunk layout ----
    int t = blockIdx.x * 256 + tid;
    int p0 = t * 8;
    int bh = p0 >> 16;
    int rem = p0 & 65535;
    int chunk = rem >> 12;
    int e = rem & 4095;
    int r = e >> 6;
    int dd0 = e & 63;
    int d0 = dd0 ^ ((r & 7) << 3);
    const float* src = Kg + ((size_t)bh * NN + chunk * 64 + r) * ND + d0;
    float4 a = *reinterpret_cast<const float4*>(src);
    float4 c4 = *reinterpret_cast<const float4*>(src + 4);
    float f[8] = {a.x, a.y, a.z, a.w, c4.x, c4.y, c4.z, c4.w};
    s16x8 hi, lo;
#pragma unroll
    for (int j = 0; j < 8; ++j) {
      short h = f2bf(f[j]);
      hi[j] = h;
      lo[j] = f2bf(f[j] - bf2f(h));
    }
    *reinterpret_cast<s16x8*>(Khi + p0) = hi;
    *reinterpret_cast<s16x8*>(Klo + p0) = lo;
  } else {
    // ---- V -> V^T bf16 [bh][d][k] ----
    int vb = blockIdx.x - 2048;
    int bh = vb >> 4;
    int kc = vb & 15;
#pragma unroll
    for (int i = 0; i < 4; ++i) {
      int e = tid + i * 256;
      int k = e >> 4, d0 = (e & 15) * 4;
      const float* src = Vg + ((size_t)bh * NN + kc * 64 + k) * ND + d0;
      float4 v = *reinterpret_cast<const float4*>(src);
      float* dst = &tile[k * 65 + d0];
      dst[0] = v.x; dst[1] = v.y; dst[2] = v.z; dst[3] = v.w;
    }
    __syncthreads();
    {
      int d = tid >> 2;
      int kk = (tid & 3) * 16;
      s16x8 o0, o1;
#pragma unroll
      for (int j = 0; j < 8; ++j) o0[j] = f2bf(tile[(kk + j) * 65 + d]);
#pragma unroll
      for (int j = 0; j < 8; ++j) o1[j] = f2bf(tile[(kk + 8 + j) * 65 + d]);
      short* dst = Vt + ((size_t)bh * ND + d) * NN + kc * 64 + kk;
      *reinterpret_cast<s16x8*>(dst) = o0;
      *reinterpret_cast<s16x8*>(dst + 8) = o1;
    }
  }
}

// ---------------- main fused kernel ---------------------------------------
__global__ __launch_bounds__(256, 3) void mrsa_main(
    const float* __restrict__ Qg, const float* __restrict__ Ag,
    const float* __restrict__ Wg, const short* __restrict__ Khi,
    const short* __restrict__ Klo, const short* __restrict__ Vt,
    float* __restrict__ outO, float* __restrict__ outW) {
  __shared__ short kbuf[16384];  // phase1: 2x(4KB hi|4KB lo); ph2/3: P bf16
  __shared__ float red0[16][4];
  __shared__ float red1[16][4];

  const int tid = threadIdx.x;
  const int lane = tid & 63;
  const int wv = tid >> 6;
  const int l4 = lane & 15;
  const int hi4 = lane >> 4;

  // Hybrid order: XCD x owns (b = x>>1, rb-half = x&1); within XCD
  // i = [rbo:3][ho:1][rbi:2][hi:3] -> A slices L2-resident across heads.
  const int x = blockIdx.x & 7;
  const int i = blockIdx.x >> 3;
  const int b = x >> 1;
  const int h = ((i >> 5) & 1) * 8 + (i & 7);
  const int rb = (x & 1) * 32 + ((i >> 6) << 2) + ((i >> 3) & 3);
  const int row0 = rb * 16;

  const size_t bh = (size_t)b * NH + h;
  const float* Qp = Qg + bh * (NN * ND);

  float wE[NT];
#pragma unroll
  for (int t = 0; t < NT; ++t) wE[t] = Wg[t * NH + h];

  const int k0 = hi4 * 8;  // MFMA k base within 32

  // Q fragments (hi/lo bf16 split), A-frag row = l4
  s16x8 qh[2], ql[2];
#pragma unroll
  for (int ks = 0; ks < 2; ++ks) {
    const float* qrow = Qp + (size_t)(row0 + l4) * ND + ks * 32 + k0;
#pragma unroll
    for (int j = 0; j < 8; ++j) {
      float f = qrow[j];
      short hb = f2bf(f);
      qh[ks][j] = hb;
      ql[ks][j] = f2bf(f - bf2f(hb));
    }
  }

  const int bcol = wv * 16 + l4;    // score col within 64-col chunk
  const int bsw = (bcol & 7) << 3;  // K LDS swizzle for this col
  const size_t kbase = bh * 65536;

  const float* Ap[NT];
#pragma unroll
  for (int t = 0; t < NT; ++t)
    Ap[t] = Ag + ((size_t)t * NB + b) * (NN * NN) +
            (size_t)(row0 + hi4 * 4) * NN + bcol;

  f32x4 sAcc[16];
  float aBuf[2][NT][4];

#define STAGE_K(cc)                                                         \
  do {                                                                      \
    size_t g0 =                                                             \
        kbase + (size_t)(cc)*4096 + (size_t)wv * 1024 + (size_t)lane * 8;   \
    short* KH = &kbuf[((cc)&1) * 8192];                                     \
    short* KL = KH + 4096;                                                  \
    gload_lds16(Khi + g0, KH + wv * 1024);                                  \
    gload_lds16(Khi + g0 + 512, KH + wv * 1024 + 512);                      \
    gload_lds16(Klo + g0, KL + wv * 1024);                                  \
    gload_lds16(Klo + g0 + 512, KL + wv * 1024 + 512);                      \
  } while (0)

#define ISSUE_A(cc)                                                         \
  do {                                                                      \
    _Pragma("unroll") for (int t = 0; t < NT; ++t) {                        \
      _Pragma("unroll") for (int r = 0; r < 4; ++r) {                       \
        aBuf[(cc)&1][t][r] = Ap[t][r * NN + (cc)*64];                       \
      }                                                                     \
    }                                                                       \
  } while (0)

  STAGE_K(0);
  ISSUE_A(0);

  // ============ Phase 1: biased S into registers ==========================
#pragma unroll
  for (int c = 0; c < 16; ++c) {
    __syncthreads();  // K(c) DMA + A(c) loads drained
    if (c < 15) {
      STAGE_K(c + 1);
      ISSUE_A(c + 1);
    }
    const short* KH = &kbuf[(c & 1) * 8192];
    const short* KL = KH + 4096;
    s16x8 kh8[2], kl8[2];
#pragma unroll
    for (int ks = 0; ks < 2; ++ks) {
      int ph = bcol * 64 + ((ks * 32 + k0) ^ bsw);
      kh8[ks] = *reinterpret_cast<const s16x8*>(&KH[ph]);
      kl8[ks] = *reinterpret_cast<const s16x8*>(&KL[ph]);
    }
    f32x4 acc = {0.f, 0.f, 0.f, 0.f};
#pragma unroll
    for (int ks = 0; ks < 2; ++ks) {
      acc = __builtin_amdgcn_mfma_f32_16x16x32_bf16(qh[ks], kh8[ks], acc, 0, 0, 0);
      acc = __builtin_amdgcn_mfma_f32_16x16x32_bf16(qh[ks], kl8[ks], acc, 0, 0, 0);
      acc = __builtin_amdgcn_mfma_f32_16x16x32_bf16(ql[ks], kh8[ks], acc, 0, 0, 0);
    }
#pragma unroll
    for (int r = 0; r < 4; ++r) {
      float bias = wE[0] * aBuf[c & 1][0][r] + wE[1] * aBuf[c & 1][1][r] +
                   wE[2] * aBuf[c & 1][2][r] + wE[3] * aBuf[c & 1][3][r];
      sAcc[c][r] = acc[r] * (1.f + bias) * 0.125f;
    }
  }

  // ============ Phase 2: softmax in registers =============================
  float mr[4];
#pragma unroll
  for (int r = 0; r < 4; ++r) {
    float m = sAcc[0][r];
#pragma unroll
    for (int c = 1; c < 16; ++c) m = fmaxf(m, sAcc[c][r]);
    mr[r] = m;
  }
#pragma unroll
  for (int off = 8; off >= 1; off >>= 1) {
#pragma unroll
    for (int r = 0; r < 4; ++r) mr[r] = fmaxf(mr[r], __shfl_xor(mr[r], off));
  }
  if (l4 == 0) {
#pragma unroll
    for (int r = 0; r < 4; ++r) red0[hi4 * 4 + r][wv] = mr[r];
  }
  __syncthreads();
  float mfin[4], inv[4];
#pragma unroll
  for (int r = 0; r < 4; ++r) {
    float4 v = *reinterpret_cast<const float4*>(&red0[hi4 * 4 + r][0]);
    mfin[r] = fmaxf(fmaxf(v.x, v.y), fmaxf(v.z, v.w));
  }
  float sr[4];
#pragma unroll
  for (int r = 0; r < 4; ++r) {
    float s = 0.f;
#pragma unroll
    for (int c = 0; c < 16; ++c) {
      float e = __expf(sAcc[c][r] - mfin[r]);
      sAcc[c][r] = e;
      s += e;
    }
    sr[r] = s;
  }
#pragma unroll
  for (int off = 8; off >= 1; off >>= 1) {
#pragma unroll
    for (int r = 0; r < 4; ++r) sr[r] += __shfl_xor(sr[r], off);
  }
  if (l4 == 0) {
#pragma unroll
    for (int r = 0; r < 4; ++r) red1[hi4 * 4 + r][wv] = sr[r];
  }
  __syncthreads();  // all waves done with K LDS -> safe to write P
#pragma unroll
  for (int r = 0; r < 4; ++r) {
    float4 v = *reinterpret_cast<const float4*>(&red1[hi4 * 4 + r][0]);
    inv[r] = 1.f / (v.x + v.y + v.z + v.w);
  }

  // ============ P pack (bf16 -> LDS [16][1024], xor-swizzled) =============
#pragma unroll
  for (int r = 0; r < 4; ++r) {
    const int lrow = hi4 * 4 + r;
    const int prow = lrow * 1024;
    const int swc = bcol ^ ((lrow & 7) << 3);
#pragma unroll
    for (int c = 0; c < 16; ++c) {
      kbuf[prow + c * 64 + swc] = f2bf(sAcc[c][r] * inv[r]);
    }
  }
  __syncthreads();

  // ============ Phase 3: out = P @ V via V^T bf16 =========================
  {
    f32x4 acc = {0.f, 0.f, 0.f, 0.f};
    const int dcol = bcol;
    const int abase = l4 * 1024;
    const int asw = (l4 & 7) << 3;
    const short* vtp = Vt + (bh * ND + (size_t)dcol) * NN;
#pragma unroll 8
    for (int kk = 0; kk < 32; ++kk) {
      int kb = kk * 32 + k0;
      s16x8 af = *reinterpret_cast<const s16x8*>(&kbuf[abase + (kb ^ asw)]);
      s16x8 bfv = *reinterpret_cast<const s16x8*>(&vtp[kb]);
      acc = __builtin_amdgcn_mfma_f32_16x16x32_bf16(af, bfv, acc, 0, 0, 0);
    }
#pragma unroll
    for (int r = 0; r < 4; ++r) {
      __builtin_nontemporal_store(
          acc[r], &outO[(bh * NN + (size_t)(row0 + hi4 * 4 + r)) * ND + dcol]);
    }
  }

  // ============ W write: coalesced float4 nt-stores from P LDS ============
#pragma unroll
  for (int rr = 0; rr < 4; ++rr) {
    const int row = wv * 4 + rr;
    const int sw8 = (row & 7) << 3;
    float* gw = outW + ((bh * NN + (size_t)(row0 + row)) << 10);
    const int prow = row * 1024;
#pragma unroll
    for (int i2 = 0; i2 < 4; ++i2) {
      int gcol = lane * 4 + i2 * 256;
      s16x4 p4 = *reinterpret_cast<const s16x4*>(&kbuf[prow + (gcol ^ sw8)]);
      f32x4 w4;
      w4[0] = bf2f(p4[0]);
      w4[1] = bf2f(p4[1]);
      w4[2] = bf2f(p4[2]);
      w4[3] = bf2f(p4[3]);
      __builtin_nontemporal_store(w4, reinterpret_cast<f32x4*>(&gw[gcol]));
    }
  }
#undef STAGE_K
#undef ISSUE_A
}

// ---------------- fallback (round-1 kernel, no workspace) ------------------
__global__ __launch_bounds__(256, 2) void mrsa_fused(
    const float* __restrict__ Qg, const float* __restrict__ Kg,
    const float* __restrict__ Vg, const float* __restrict__ Ag,
    const float* __restrict__ Wg, float* __restrict__ outO,
    float* __restrict__ outW) {
  __shared__ short KsHi[64 * 64];
  __shared__ short KsLo[64 * 64];
  __shared__ float Ss[16 * 1024];
  const int tid = threadIdx.x;
  const int lane = tid & 63;
  const int wv = tid >> 6;
  const int rb = blockIdx.x;
  const int h = blockIdx.y;
  const int b = blockIdx.z;
  const int row0 = rb * 16;
  const size_t bh = (size_t)b * NH + h;
  const float* Qp = Qg + bh * (NN * ND);
  const float* Kp = Kg + bh * (NN * ND);
  const float* Vp = Vg + bh * (NN * ND);
  float wE[NT];
#pragma unroll
  for (int t = 0; t < NT; ++t) wE[t] = Wg[t * NH + h];
  const int arow = lane & 15;
  const int k0 = (lane >> 4) * 8;
  s16x8 qh[2], ql[2];
#pragma unroll
  for (int ks = 0; ks < 2; ++ks) {
    const float* qrow = Qp + (size_t)(row0 + arow) * ND + ks * 32 + k0;
#pragma unroll
    for (int j = 0; j < 8; ++j) {
      float f = qrow[j];
      short hi = f2bf(f);
      qh[ks][j] = hi;
      ql[ks][j] = f2bf(f - bf2f(hi));
    }
  }
  const int bcol = wv * 16 + (lane & 15);
  const int bsw = (bcol & 7) << 3;
  for (int c = 0; c < 16; ++c) {
#pragma unroll
    for (int i = 0; i < 4; ++i) {
      int e4 = tid + i * 256;
      int r = e4 >> 4;
      int d0 = (e4 & 15) * 4;
      float4 kv = *reinterpret_cast<const float4*>(
          Kp + (size_t)(c * 64 + r) * ND + d0);
      float kf[4];
      kf[0] = kv.x; kf[1] = kv.y; kf[2] = kv.z; kf[3] = kv.w;
      s16x4 hi4, lo4;
#pragma unroll
      for (int j = 0; j < 4; ++j) {
        short hi = f2bf(kf[j]);
        hi4[j] = hi;
        lo4[j] = f2bf(kf[j] - bf2f(hi));
      }
      int sw = r * 64 + (d0 ^ ((r & 7) << 3));
      *reinterpret_cast<s16x4*>(&KsHi[sw]) = hi4;
      *reinterpret_cast<s16x4*>(&KsLo[sw]) = lo4;
    }
    __syncthreads();
    f32x4 acc = {0.f, 0.f, 0.f, 0.f};
#pragma unroll
    for (int ks = 0; ks < 2; ++ks) {
      int kb = ks * 32 + k0;
      int ph = bcol * 64 + (kb ^ bsw);
      s16x8 kh8 = *reinterpret_cast<const s16x8*>(&KsHi[ph]);
      s16x8 kl8 = *reinterpret_cast<const s16x8*>(&KsLo[ph]);
      acc = __builtin_amdgcn_mfma_f32_16x16x32_bf16(qh[ks], kh8, acc, 0, 0, 0);
      acc = __builtin_amdgcn_mfma_f32_16x16x32_bf16(qh[ks], kl8, acc, 0, 0, 0);
      acc = __builtin_amdgcn_mfma_f32_16x16x32_bf16(ql[ks], kh8, acc, 0, 0, 0);
    }
    int gcol = c * 64 + bcol;
#pragma unroll
    for (int r = 0; r < 4; ++r) {
      int lrow = (lane >> 4) * 4 + r;
      int grow = row0 + lrow;
      float bias = 0.f;
#pragma unroll
      for (int t = 0; t < NT; ++t)
        bias += wE[t] *
                Ag[((size_t)t * NB + b) * (NN * NN) + (size_t)grow * NN + gcol];
      Ss[lrow * 1024 + (gcol ^ ((lrow & 7) << 3))] =
          acc[r] * (1.f + bias) * 0.125f;
    }
    __syncthreads();
  }
#pragma unroll
  for (int rr = 0; rr < 4; ++rr) {
    int lrow = wv * 4 + rr;
    float* srow = &Ss[lrow * 1024];
    int sw = (lrow & 7) << 3;
    float m = -3.4e38f;
#pragma unroll
    for (int i = 0; i < 16; ++i) m = fmaxf(m, srow[i * 64 + lane]);
#pragma unroll
    for (int off = 32; off; off >>= 1) m = fmaxf(m, __shfl_xor(m, off));
    float ev[16];
    float lsum = 0.f;
#pragma unroll
    for (int i = 0; i < 16; ++i) {
      float e = __expf(srow[i * 64 + lane] - m);
      ev[i] = e;
      lsum += e;
    }
#pragma unroll
    for (int off = 32; off; off >>= 1) lsum += __shfl_xor(lsum, off);
    float inv = 1.f / lsum;
    float* gw = outW + (bh * NN + (size_t)(row0 + lrow)) * NN;
#pragma unroll
    for (int i = 0; i < 16; ++i) {
      float w = ev[i] * inv;
      int p = i * 64 + lane;
      srow[p] = w;
      gw[p ^ sw] = w;
    }
  }
  __syncthreads();
  {
    f32x4 acc = {0.f, 0.f, 0.f, 0.f};
    const int dcol = wv * 16 + (lane & 15);
    const int asw = (arow & 7) << 3;
    const float* srow = &Ss[arow * 1024];
#pragma unroll 2
    for (int kk = 0; kk < 32; ++kk) {
      int kb = kk * 32 + k0;
      int ph = kb ^ asw;
      float4 a0 = *reinterpret_cast<const float4*>(&srow[ph]);
      float4 a1 = *reinterpret_cast<const float4*>(&srow[ph + 4]);
      s16x8 af, bfv;
      af[0] = f2bf(a0.x); af[1] = f2bf(a0.y);
      af[2] = f2bf(a0.z); af[3] = f2bf(a0.w);
      af[4] = f2bf(a1.x); af[5] = f2bf(a1.y);
      af[6] = f2bf(a1.z); af[7] = f2bf(a1.w);
      const float* vcol = Vp + (size_t)kb * ND + dcol;
#pragma unroll
      for (int j = 0; j < 8; ++j) bfv[j] = f2bf(vcol[j * ND]);
      acc = __builtin_amdgcn_mfma_f32_16x16x32_bf16(af, bfv, acc, 0, 0, 0);
    }
#pragma unroll
    for (int r = 0; r < 4; ++r) {
      int lrow = (lane >> 4) * 4 + r;
      outO[(bh * NN + (size_t)(row0 + lrow)) * ND + dcol] = acc[r];
    }
  }
}

extern "C" void kernel_launch(void* const* d_in, const int* in_sizes, int n_in,
                              void* d_out, int out_size, void* d_ws,
                              size_t ws_size, hipStream_t stream) {
  const float* Q = (const float*)d_in[0];
  const float* K = (const float*)d_in[1];
  const float* V = (const float*)d_in[2];
  const float* A = (const float*)d_in[3];
  const float* wE = (const float*)d_in[4];
  float* out = (float*)d_out;
  float* outW = out + (size_t)NB * NH * NN * ND;

  const size_t nElem = (size_t)NB * NH * NN * ND;  // 4194304
  const size_t needK = 3 * nElem * sizeof(short);  // Khi + Klo + Vt (24MB)
  if (ws_size >= needK) {
    short* Khi = (short*)d_ws;
    short* Klo = Khi + nElem;
    short* Vt = Klo + nElem;
    hipLaunchKernelGGL(pack_kv, dim3(3072), dim3(256), 0, stream, K, V, Khi,
                       Klo, Vt);
    hipLaunchKernelGGL(mrsa_main, dim3(4096), dim3(256), 0, stream, Q, A, wE,
                       Khi, Klo, Vt, out, outW);
  } else {
    dim3 grid(NN / 16, NH, NB);
    hipLaunchKernelGGL(mrsa_fused, grid, dim3(256), 0, stream, Q, K, V, A, wE,
                       out, outW);
  }
}